// Round 4
// baseline (6780.729 us; speedup 1.0000x reference)
//
#include <hip/hip_runtime.h>

// LSTM: L=2, B=64, T=512, H=1024
#define BB 64
#define TT 512
#define HH 1024
#define NL 2
#define G4 4096   // 4H
#define D2 2048   // 2H
#define TC 64     // timestep chunk for Gx buffer
#define NCHUNK (TT / TC)

typedef __attribute__((ext_vector_type(8))) short bf16x8;
typedef __attribute__((ext_vector_type(4))) float f32x4;

__device__ inline unsigned short f2bf(float f) {
  union { float f; unsigned u; } v; v.f = f;
  unsigned r = v.u + 0x7FFFu + ((v.u >> 16) & 1u);
  return (unsigned short)(r >> 16);
}

__device__ inline float sigm(float x) { return 1.0f / (1.0f + __expf(-x)); }
__device__ inline float tanhfast(float x) { return 2.0f / (1.0f + __expf(-2.0f * x)) - 1.0f; }

// ---- LLC-coherent (cross-XCD) accesses: sc0 sc1 bypass L1+L2, no cache inv ----
__device__ inline bf16x8 ld_h16(const unsigned short* p) {
  bf16x8 r;
  asm volatile("global_load_dwordx4 %0, %1, off sc0 sc1" : "=v"(r) : "v"(p) : "memory");
  return r;
}
__device__ inline unsigned ld_flag(const unsigned* p) {
  unsigned r;
  asm volatile("global_load_dword %0, %1, off sc0 sc1\n\t"
               "s_waitcnt vmcnt(0)"
               : "=v"(r) : "v"(p) : "memory");
  return r;
}
__device__ inline void st_flag(unsigned* p, unsigned v) {
  asm volatile("global_store_dword %0, %1, off sc0 sc1" :: "v"(p), "v"(v) : "memory");
}
__device__ inline void st_bf(unsigned short* p, unsigned v) {
  asm volatile("global_store_short %0, %1, off sc0 sc1" :: "v"(p), "v"(v) : "memory");
}
// normal cached 16B load, volatile (pins W into registers, no remat/sink)
__device__ inline bf16x8 ld16_pin(const unsigned short* p) {
  bf16x8 r;
  asm volatile("global_load_dwordx4 %0, %1, off" : "=v"(r) : "v"(p));
  return r;
}

// ---------------- fp32 -> bf16 bulk convert ----------------
__global__ __launch_bounds__(256) void k_cvt(const float* __restrict__ src,
                                             unsigned short* __restrict__ dst, int n4) {
  int i = blockIdx.x * blockDim.x + threadIdx.x;
  int stride = gridDim.x * blockDim.x;
  for (; i < n4; i += stride) {
    float4 v = ((const float4*)src)[i];
    ushort4 o;
    o.x = f2bf(v.x); o.y = f2bf(v.y); o.z = f2bf(v.z); o.w = f2bf(v.w);
    ((ushort4*)dst)[i] = o;
  }
}

__global__ void k_zero(unsigned* __restrict__ p, int n) {
  int i = blockIdx.x * blockDim.x + threadIdx.x;
  if (i < n) p[i] = 0;
}

__global__ void k_biasperm(const float* __restrict__ b_in, float* __restrict__ bperm) {
  int i = blockIdx.x * blockDim.x + threadIdx.x;
  if (i < NL * G4) {
    int l = i >> 12, nn = i & 4095;
    bperm[i] = b_in[l * G4 + (nn & 3) * HH + (nn >> 2)];
  }
}

__global__ void k_init(const float* __restrict__ h0, const float* __restrict__ c0,
                       unsigned short* __restrict__ hbf0, float* __restrict__ cst, int l) {
  int i = blockIdx.x * blockDim.x + threadIdx.x;
  if (i < BB * HH) {
    hbf0[i] = f2bf(h0[l * BB * HH + i]);
    cst[i] = c0[l * BB * HH + i];
  }
}

// ---------------- x-projection GEMM (verified R1-R3) ----------------
__global__ __launch_bounds__(256) void k_xgemm(const unsigned short* __restrict__ xbf,
                                               const unsigned short* __restrict__ wbf,
                                               const float* __restrict__ bperm,
                                               float* __restrict__ gx,
                                               int layer, int t0) {
  __shared__ short lds[2 * 8192];
  short* Ald = lds;
  short* Bld = lds + 8192;
  const int tid = threadIdx.x;
  const int lane = tid & 63;
  const int w = tid >> 6;
  const int bx = blockIdx.x, by = blockIdx.y;
  const unsigned short* wb = wbf + (size_t)layer * G4 * D2;

  f32x4 acc[4][4] = {};
  const int pslot = lane & 7;

  for (int kc = 0; kc < 16; ++kc) {
    __syncthreads();
    const int k0 = kc * 64;
#pragma unroll
    for (int i = 0; i < 4; ++i) {
      int r = (w * 4 + i) * 8 + (lane >> 3);
      int lslot = pslot ^ (r & 7);
      {
        int mg = by * 128 + r;
        int b = mg & 63, t = t0 + (mg >> 6);
        const unsigned short* src = xbf + ((size_t)(b * TT + t)) * HH + k0 + lslot * 8;
        __builtin_amdgcn_global_load_lds((const __attribute__((address_space(1))) void*)src,
                                         (__attribute__((address_space(3))) void*)(Ald + (w * 4 + i) * 512),
                                         16, 0, 0);
      }
      {
        int ng = bx * 128 + r;
        int wrow = (ng & 3) * HH + (ng >> 2);
        const unsigned short* src = wb + (size_t)wrow * D2 + k0 + lslot * 8;
        __builtin_amdgcn_global_load_lds((const __attribute__((address_space(1))) void*)src,
                                         (__attribute__((address_space(3))) void*)(Bld + (w * 4 + i) * 512),
                                         16, 0, 0);
      }
    }
    asm volatile("s_waitcnt vmcnt(0)" ::: "memory");
    __syncthreads();

#pragma unroll
    for (int kk = 0; kk < 2; ++kk) {
      bf16x8 afr[4], bfr[4];
      int ls = kk * 4 + (lane >> 4);
#pragma unroll
      for (int f = 0; f < 4; ++f) {
        int ra = (w >> 1) * 64 + f * 16 + (lane & 15);
        int ps = ls ^ (ra & 7);
        afr[f] = *(const bf16x8*)((const char*)Ald + ra * 128 + ps * 16);
        int rb = (w & 1) * 64 + f * 16 + (lane & 15);
        int psb = ls ^ (rb & 7);
        bfr[f] = *(const bf16x8*)((const char*)Bld + rb * 128 + psb * 16);
      }
#pragma unroll
      for (int fi = 0; fi < 4; ++fi)
#pragma unroll
        for (int fj = 0; fj < 4; ++fj)
          acc[fi][fj] = __builtin_amdgcn_mfma_f32_16x16x32_bf16(afr[fi], bfr[fj], acc[fi][fj], 0, 0, 0);
    }
  }

  const float* bp = bperm + layer * G4;
#pragma unroll
  for (int fj = 0; fj < 4; ++fj) {
    int col = bx * 128 + (w & 1) * 64 + fj * 16 + (lane & 15);
    float bv = bp[col];
#pragma unroll
    for (int fi = 0; fi < 4; ++fi) {
      int mg = by * 128 + (w >> 1) * 64 + fi * 16 + (lane >> 4) * 4;
#pragma unroll
      for (int r = 0; r < 4; ++r)
        gx[(size_t)(mg + r) * G4 + col] = acc[fi][fj][r] + bv;
    }
  }
}

// ---------------- persistent recurrent chunk v4 ----------------
// 256 WGs x 256 thr. WG = (bg,cg): bg = wg>>6 -> batches [bg*16,+16);
// cg = wg&63 -> 64 interleaved cols = units [cg*16,+16) x 4 gates.
// Wave wv: K-octet [wv*256,+256), W in 128 VGPRs (volatile-pinned).
// Flags: one word per WG (flags[bg*64+cg] = global step done). Wave wv
// polls only its 16 producers (one 64B load). Critical path per step:
// poll -> h K-slice load -> 32 MFMA -> LDS partial -> barrier ->
// elementwise -> coherent h store -> vmcnt(0) -> barrier -> flag store.
// xnext/dout/gx-prefetch issued after the flag (off critical path).
__global__ __launch_bounds__(256, 2) void k_steps64(unsigned short* __restrict__ hbf,
                                                    const unsigned short* __restrict__ wbf,
                                                    const float* __restrict__ gx,
                                                    float* __restrict__ cst,
                                                    float* __restrict__ dout,
                                                    unsigned short* __restrict__ xnext,
                                                    unsigned* __restrict__ flags,
                                                    int layer, int t0) {
  __shared__ __align__(16) float gl[4][64][24];
  const int tid = threadIdx.x;
  const int lane = tid & 63;
  const int wv = tid >> 6;
  const int wg = blockIdx.x;
  const int bg = wg >> 6, cg = wg & 63;
  const int b0 = bg * 16;
  const int u0 = cg * 16;
  const int n0 = cg * 64;
  const int k0 = wv * 256;
  const unsigned lgen = (unsigned)(layer * TT);

  // ---- W preload: 4 n-tiles x 8 k-slices = 128 VGPRs (pinned) ----
  bf16x8 wreg[4][8];
  {
    const unsigned short* wbase = wbf + (size_t)layer * G4 * D2;
#pragma unroll
    for (int nt = 0; nt < 4; ++nt) {
      int n = n0 + nt * 16 + (lane & 15);
      const unsigned short* wr = wbase + (size_t)((n & 3) * HH + (n >> 2)) * D2
                                 + HH + k0 + (lane >> 4) * 8;
#pragma unroll
      for (int ks = 0; ks < 8; ++ks)
        wreg[nt][ks] = ld16_pin(wr + ks * 32);
    }
    asm volatile("s_waitcnt vmcnt(0)" ::: "memory");
    __builtin_amdgcn_sched_barrier(0);
  }

  // ---- per-thread elementwise ownership: (batch b0+eb, unit u0+eu) ----
  const int eb = tid >> 4;   // 0..15
  const int eu = tid & 15;   // 0..15
  float creg = cst[(size_t)(b0 + eb) * HH + u0 + eu];
  const float* gxp = gx + (size_t)(b0 + eb) * G4 + (u0 + eu) * 4;
  const unsigned* fbase = flags + bg * 64 + wv * 16 + (lane & 15);
  unsigned* myflag = flags + wg;

  float4 gxv = *(const float4*)gxp;   // tt = 0 prefetch

  for (int tt = 0; tt < TC; ++tt) {
    const int t = t0 + tt;
    const unsigned G = lgen + (unsigned)t;

    if (tt > 0) {
      while (1) {
        unsigned v = ld_flag(fbase);
        if (__all((int)(v >= G))) break;
        __builtin_amdgcn_s_sleep(1);
      }
    }

    // ---- h K-slice from LLC ----
    const unsigned short* hsrc = hbf + (size_t)(t & 1) * (BB * HH)
                                 + (size_t)(b0 + (lane & 15)) * HH + k0 + (lane >> 4) * 8;
    bf16x8 areg[8];
#pragma unroll
    for (int ks = 0; ks < 8; ++ks) areg[ks] = ld_h16(hsrc + ks * 32);
    asm volatile("s_waitcnt vmcnt(0)" ::: "memory");
    __builtin_amdgcn_sched_barrier(0);

    // ---- 32 MFMA: 4 col-tiles x 8 k-slices ----
    f32x4 acc[4] = {};
#pragma unroll
    for (int ks = 0; ks < 8; ++ks)
#pragma unroll
      for (int nt = 0; nt < 4; ++nt)
        acc[nt] = __builtin_amdgcn_mfma_f32_16x16x32_bf16(areg[ks], wreg[nt][ks], acc[nt], 0, 0, 0);

    // ---- partial-K write ----
#pragma unroll
    for (int nt = 0; nt < 4; ++nt)
      *(f32x4*)&gl[wv][nt * 16 + (lane & 15)][(lane >> 4) * 4] = acc[nt];
    __syncthreads();

    // ---- fused elementwise (1 output/thread) ----
    float fg = gxv.x, ig = gxv.y, gg = gxv.z, og = gxv.w;
    {
      const int c0 = eu * 4;
#pragma unroll
      for (int w2 = 0; w2 < 4; ++w2) {
        fg += gl[w2][c0 + 0][eb];
        ig += gl[w2][c0 + 1][eb];
        gg += gl[w2][c0 + 2][eb];
        og += gl[w2][c0 + 3][eb];
      }
    }
    float cn = sigm(fg) * creg + sigm(ig) * tanhfast(gg);
    float hn = sigm(og) * tanhfast(cn);
    creg = cn;
    unsigned short hb = f2bf(hn);

    // ---- coherent h store -> drain -> barrier -> flag ----
    st_bf(hbf + (size_t)((t + 1) & 1) * (BB * HH) + (size_t)(b0 + eb) * HH + u0 + eu,
          (unsigned)hb);
    asm volatile("s_waitcnt vmcnt(0)" ::: "memory");
    __syncthreads();
    if (tid == 0) st_flag(myflag, G + 1u);

    // ---- off-critical-path stores + next gx prefetch ----
    if (layer == 0) {
      xnext[((size_t)(b0 + eb) * TT + t) * HH + u0 + eu] = hb;
      if (t == TT - 1) dout[((size_t)(b0 + eb) * TT + t) * HH + u0 + eu] = hn;
    } else {
      dout[((size_t)(b0 + eb) * TT + t) * HH + u0 + eu] = hn;
    }
    const int ttn = (tt < TC - 1) ? tt + 1 : tt;
    gxv = *(const float4*)(gxp + (size_t)ttn * BB * G4);
  }

  cst[(size_t)(b0 + eb) * HH + u0 + eu] = creg;
}

// h_n[l] = out[:, T-1, :], c_n[l] = c_state
__global__ void k_finals(const float* __restrict__ cst, float* __restrict__ dout, int layer) {
  int i = blockIdx.x * blockDim.x + threadIdx.x;
  if (i < BB * HH) {
    int b = i >> 10, u = i & 1023;
    dout[(size_t)BB * TT * HH + (size_t)layer * BB * HH + i] =
        dout[((size_t)b * TT + (TT - 1)) * HH + u];
    dout[(size_t)BB * TT * HH + (size_t)NL * BB * HH + (size_t)layer * BB * HH + i] = cst[i];
  }
}

extern "C" void kernel_launch(void* const* d_in, const int* in_sizes, int n_in,
                              void* d_out, int out_size, void* d_ws, size_t ws_size,
                              hipStream_t stream) {
  const float* x = (const float*)d_in[0];
  const float* W = (const float*)d_in[1];
  const float* bias = (const float*)d_in[2];
  const float* h0 = (const float*)d_in[3];
  const float* c0 = (const float*)d_in[4];
  float* out = (float*)d_out;

  char* ws = (char*)d_ws;
  unsigned short* wbf = (unsigned short*)(ws + 0);            // 33,554,432 B
  unsigned short* xbf = (unsigned short*)(ws + 33554432);     // 67,108,864 B
  float* gx = (float*)(ws + 100663296);                       // 67,108,864 B
  unsigned short* hbf = (unsigned short*)(ws + 167772160);    // 262,144 B
  float* cst = (float*)(ws + 168034304);                      // 262,144 B
  float* bperm = (float*)(ws + 168296448);                    // 32,768 B
  unsigned* flags = (unsigned*)(ws + 168329216);              // 1,024 B (256 uints)

  k_zero<<<1, 256, 0, stream>>>(flags, 256);
  k_cvt<<<2048, 256, 0, stream>>>(W, wbf, NL * G4 * D2 / 4);
  k_cvt<<<2048, 256, 0, stream>>>(x, xbf, BB * TT * HH / 4);
  k_biasperm<<<(NL * G4 + 255) / 256, 256, 0, stream>>>(bias, bperm);

  for (int l = 0; l < NL; ++l) {
    k_init<<<BB * HH / 256, 256, 0, stream>>>(h0, c0, hbf, cst, l);
    for (int c = 0; c < NCHUNK; ++c) {
      k_xgemm<<<dim3(32, 32), 256, 0, stream>>>(xbf, wbf, bperm, gx, l, c * TC);
      k_steps64<<<256, 256, 0, stream>>>(hbf, wbf, gx, cst, out,
                                         (l == 0) ? xbf : (unsigned short*)nullptr,
                                         flags, l, c * TC);
    }
    k_finals<<<256, 256, 0, stream>>>(cst, out, l);
  }
}